// Round 4
// baseline (438.708 us; speedup 1.0000x reference)
//
#include <hip/hip_runtime.h>

#define SLOPE 0.01f

typedef float f32x4 __attribute__((ext_vector_type(4)));

// Weight pointers passed by value in the kernarg segment (160 B). The layer
// loop is fully unrolled -> h.w[L]/h.b[L] are compile-time kernarg offsets ->
// uniform pointers -> weights become scalar broadcast operands.
struct Half5 { const float* w[5]; const float* b[5]; };
struct WPtrs { Half5 logs; Half5 aff; };

// 5-layer 8->8 MLP, leaky ReLU after first 4 layers.
// w[L]: 64 fp32 row-major (out[j] += w[j*8+k] * x[k]); b[L]: 8 fp32.
__device__ __forceinline__ void mlp8(const Half5& h, const float x[8], float out[8]) {
    float a[8];
    #pragma unroll
    for (int j = 0; j < 8; ++j) a[j] = x[j];
    #pragma unroll
    for (int L = 0; L < 5; ++L) {
        const float* __restrict__ wl = h.w[L];
        const float* __restrict__ bl = h.b[L];
        float t[8];
        #pragma unroll
        for (int j = 0; j < 8; ++j) {
            float acc = bl[j];
            #pragma unroll
            for (int k = 0; k < 8; ++k)
                acc = fmaf(wl[j * 8 + k], a[k], acc);
            t[j] = acc;
        }
        #pragma unroll
        for (int j = 0; j < 8; ++j)
            a[j] = (L < 4) ? fmaxf(t[j], SLOPE * t[j]) : t[j];
    }
    #pragma unroll
    for (int j = 0; j < 8; ++j) out[j] = a[j];
}

// Measured ledger on this problem (kernel-only = dur_us - ~313us harness fills):
//   strided through-L2:            ~120-123 us
//   strided + nt stores:            224 us (partial-line nt -> 1.5x write amp)
//   LDS corner-turn, nt both sides: ~115 us (best so far)
// This version refines the corner turn: cached loads (the 6.29 TB/s copy
// ceiling was measured with cached loads; nt only proven needed on stores),
// and pass-through lanes (lane&3 < 2 hold only zl-half float4s) store straight
// from load registers -- no LDS round-trip, stores can overlap compute.
#define ROWSTRIDE 17   // 16 data + 1 pad; gcd(17,32)=1 -> conflict-free row reads

__global__ void __launch_bounds__(256)
coupling_kernel(const f32x4* __restrict__ z,   // 4 x float4 per row (16 fp32)
                WPtrs p,
                f32x4* __restrict__ out,
                int batch) {
    // Per-wave private chunk: 64 rows x 17 floats = 4352 B; 4 waves = 17408 B.
    // No cross-wave sharing -> no __syncthreads(); same-wave LDS ordering is
    // enforced by compiler-inserted lgkmcnt waits.
    __shared__ float lds[4][64 * ROWSTRIDE];

    const int tid  = threadIdx.x;
    const int lane = tid & 63;
    const int wv   = tid >> 6;
    float* __restrict__ L = lds[wv];

    const long long waveRow0 = (long long)blockIdx.x * 256 + (long long)wv * 64;
    const long long f4base   = waveRow0 * 4;
    const long long f4limit  = (long long)batch * 4;
    const int a = lane >> 2;          // row sub-index in corner turn
    const int b = lane & 3;           // float4 slot within a row (fixed per lane!)
    const bool left = (b < 2);        // this lane's float4s are zl-half -> pass-through

    // ---- Phase 1: fully-coalesced cached loads (1 KB/inst), kept in regs ----
    f32x4 v[4];
    #pragma unroll
    for (int i = 0; i < 4; ++i) {
        long long gi = f4base + (long long)(i * 64 + lane);
        f32x4 t = {0.f, 0.f, 0.f, 0.f};
        if (gi < f4limit) t = z[gi];
        v[i] = t;
    }
    // Corner-turn into LDS so phase 2 can read row-major.
    #pragma unroll
    for (int i = 0; i < 4; ++i) {
        const int w0 = (i * 16 + a) * ROWSTRIDE + b * 4;
        L[w0 + 0] = v[i].x; L[w0 + 1] = v[i].y; L[w0 + 2] = v[i].z; L[w0 + 3] = v[i].w;
    }

    // ---- Phase 2: each lane computes its own row out of LDS ----
    const long long row = waveRow0 + lane;
    if (row < batch) {
        const int r0 = lane * ROWSTRIDE;
        float zl[8], zr[8];
        #pragma unroll
        for (int j = 0; j < 8; ++j) zl[j] = L[r0 + j];
        #pragma unroll
        for (int j = 0; j < 8; ++j) zr[j] = L[r0 + 8 + j];

        float log_s[8], bb[8];
        mlp8(p.logs, zl, log_s);
        mlp8(p.aff,  zl, bb);

        // yr overwrites the zr half in LDS; zl half untouched.
        #pragma unroll
        for (int k = 0; k < 8; ++k)
            L[r0 + 8 + k] = fmaf(__expf(log_s[k]), zr[k], bb[k]);
    }

    // ---- Phase 3: nt full-line stores (proven clean WRITE_SIZE in R2) ----
    // left lanes: value == load register (bit-exact passthrough, no LDS dep,
    // compiler may overlap these stores with phase 2). right lanes: yr from LDS.
    #pragma unroll
    for (int i = 0; i < 4; ++i) {
        long long gi = f4base + (long long)(i * 64 + lane);
        if (gi < f4limit) {
            f32x4 o;
            if (left) {
                o = v[i];
            } else {
                const int w0 = (i * 16 + a) * ROWSTRIDE + b * 4;
                o = f32x4{ L[w0 + 0], L[w0 + 1], L[w0 + 2], L[w0 + 3] };
            }
            __builtin_nontemporal_store(o, out + gi);
        }
    }
}

extern "C" void kernel_launch(void* const* d_in, const int* in_sizes, int n_in,
                              void* d_out, int out_size, void* d_ws, size_t ws_size,
                              hipStream_t stream) {
    const int batch = in_sizes[0] / 16;

    WPtrs p;
    if (n_in >= 21) {
        // Lists flattened into 20 separate device arrays: pass pointers
        // directly as kernel args (no memcpy staging).
        for (int i = 0; i < 5; ++i) {
            p.logs.w[i] = (const float*)d_in[1 + i];    // ws_logs[i]: 8x8
            p.logs.b[i] = (const float*)d_in[6 + i];    // bs_logs[i]: 8
            p.aff.w[i]  = (const float*)d_in[11 + i];   // ws_b[i]:    8x8
            p.aff.b[i]  = (const float*)d_in[16 + i];   // bs_b[i]:    8
        }
    } else {
        const float* wl = (const float*)d_in[1];
        const float* bl = (const float*)d_in[2];
        const float* wv = (const float*)d_in[3];
        const float* bv = (const float*)d_in[4];
        for (int i = 0; i < 5; ++i) {
            p.logs.w[i] = wl + i * 64;
            p.logs.b[i] = bl + i * 8;
            p.aff.w[i]  = wv + i * 64;
            p.aff.b[i]  = bv + i * 8;
        }
    }

    int threads = 256;
    int blocks = (batch + threads - 1) / threads;
    coupling_kernel<<<blocks, threads, 0, stream>>>(
        (const f32x4*)d_in[0], p, (f32x4*)d_out, batch);
}